// Round 1
// baseline (353.154 us; speedup 1.0000x reference)
//
#include <hip/hip_runtime.h>
#include <math.h>

#define DDIM 128
#define NSEQ 8192
#define CHUNK 32
#define NCHUNK 256   // 8192/32
#define GROUP 8
#define NGROUP 32    // 256/8
#define NTRI 45      // lower-triangular entries (L,q), q<=L, L=0..8

#define TRI(L,q) ((L)*((L)+1)/2 + (q))

// ws layout (bytes)
#define OFF_PHAT 0                    // float2 [4][8][128]   = 32768 B
#define OFF_AB   32768                // float2 [8192][8]     = 524288 B
#define OFF_MC   557056               // float2 [256][45][128]= 11796480 B
#define OFF_MG   12353536             // float2 [32][45][128] = 1474560 B
// total ~13.2 MB

// ---------------------------------------------------------------- setup ----
__global__ __launch_bounds__(1024)
void sk_setup(const int* __restrict__ seq,
              const float* __restrict__ hw,   // [8][128][4]
              const float* __restrict__ sw,   // [8][4]
              float2* __restrict__ phat,      // out [4][8][128]
              float2* __restrict__ ab)        // out [8192][8]
{
  __shared__ float probs[32*128];
  __shared__ float twc[128], tws[128];
  const int tid  = threadIdx.x;
  const int wave = tid >> 6, lane = tid & 63;

  // softmax over d for each (p,c) row; one wave per row, 2 rows per wave
  for (int r = wave; r < 32; r += 16) {
    const int p = r >> 2, c = r & 3;
    float h0 = hw[p*512 + lane*4 + c];
    float h1 = hw[p*512 + (lane+64)*4 + c];
    float mx = fmaxf(h0, h1);
    #pragma unroll
    for (int off = 1; off < 64; off <<= 1) mx = fmaxf(mx, __shfl_xor(mx, off));
    float e0 = expf(h0 - mx), e1 = expf(h1 - mx);
    float s = e0 + e1;
    #pragma unroll
    for (int off = 1; off < 64; off <<= 1) s += __shfl_xor(s, off);
    float inv = 1.0f / s;
    probs[r*128 + lane]      = e0 * inv;
    probs[r*128 + lane + 64] = e1 * inv;
  }
  if (tid < 128) {
    float th = 6.28318530717958647692f * (float)tid / 128.0f;
    twc[tid] = cosf(th);
    tws[tid] = sinf(th);
  }
  __syncthreads();

  // forward DFT of each prob row: phat[c][p][k] = sum_j probs[r][j] e^{-2pi i jk/128}
  for (int o = tid; o < 4096; o += 1024) {
    const int r = o >> 7, k = o & 127;
    const int p = r >> 2, c = r & 3;
    float ar = 0.f, ai = 0.f;
    for (int j = 0; j < 128; ++j) {
      float pv = probs[r*128 + j];
      int w = (j * k) & 127;
      ar += pv * twc[w];
      ai -= pv * tws[w];
    }
    phat[(c*8 + p)*128 + k] = make_float2(ar, ai);
  }

  // per-step coefficients: a = gate ? 1-z : 1 ; b = gate ? z*sigmoid(sw[L-1][c]) : 0
  for (int n = tid; n < NSEQ*8; n += 1024) {
    const int i = n >> 3, Lm1 = n & 7, L = Lm1 + 1;
    int c = seq[i];
    bool valid = (c >= 0) && (c < 4);
    int cc = min(max(c, 0), 3);
    bool gate = valid && (L <= i + 1);
    float z  = (float)L / (float)(i + 1);
    float sg = 1.0f / (1.0f + expf(-sw[Lm1*4 + cc]));
    float a = gate ? (1.0f - z) : 1.0f;
    float b = gate ? (z * sg) : 0.0f;
    ab[n] = make_float2(a, b);
  }
}

// ------------------------------------------------------- chunk matrices ----
// Each block builds the 9x9 lower-triangular complex transfer matrix of its
// 32-step chunk, per frequency (lane = k). All M indices compile-time.
__global__ __launch_bounds__(128)
void sk_chunk(const int* __restrict__ seq,
              const float2* __restrict__ phat_g,
              const float2* __restrict__ ab_g,
              float2* __restrict__ mc)   // out [chunk][entry][k]
{
  __shared__ float2 phS[4096];      // [c][p][k]
  __shared__ float2 abS[CHUNK*8];
  __shared__ int    chS[CHUNK];
  const int tid = threadIdx.x;
  const int m   = blockIdx.x;

  for (int i2 = tid; i2 < 4096; i2 += 128)     phS[i2] = phat_g[i2];
  for (int i2 = tid; i2 < CHUNK*8; i2 += 128)  abS[i2] = ab_g[m*CHUNK*8 + i2];
  if (tid < CHUNK) chS[tid] = seq[m*CHUNK + tid];
  __syncthreads();

  float Mr[NTRI], Mi[NTRI];
  #pragma unroll
  for (int e = 0; e < NTRI; ++e) { Mr[e] = 0.f; Mi[e] = 0.f; }
  #pragma unroll
  for (int L = 0; L <= 8; ++L) Mr[TRI(L,L)] = 1.0f;

  for (int t = 0; t < CHUNK; ++t) {
    const int c = chS[t];
    // simultaneous row update, done in-place in DESCENDING L:
    // row_L <- a*row_L + b*Phat[L-1]*row_{L-1}  (row_{L-1} still old)
    #pragma unroll
    for (int L = 8; L >= 1; --L) {
      float2 abv = abS[t*8 + (L-1)];
      float2 Pv  = phS[(c*8 + (L-1))*128 + tid];
      const float a = abv.x, b = abv.y;
      #pragma unroll
      for (int q = 0; q < L; ++q) {
        float xr = Mr[TRI(L-1,q)], xi = Mi[TRI(L-1,q)];
        float tr = Pv.x*xr - Pv.y*xi;
        float ti = Pv.x*xi + Pv.y*xr;
        Mr[TRI(L,q)] = a*Mr[TRI(L,q)] + b*tr;
        Mi[TRI(L,q)] = a*Mi[TRI(L,q)] + b*ti;
      }
      Mr[TRI(L,L)] *= a;
      Mi[TRI(L,L)] *= a;
    }
  }
  #pragma unroll
  for (int e = 0; e < NTRI; ++e)
    mc[(m*NTRI + e)*128 + tid] = make_float2(Mr[e], Mi[e]);
}

// -------------------------------------------------- combine 8 chunks -> 1 --
__global__ __launch_bounds__(128)
void sk_group(const float2* __restrict__ mc, float2* __restrict__ mg)
{
  const int tid = threadIdx.x;
  const int g   = blockIdx.x;

  float Ar[NTRI], Ai[NTRI];
  #pragma unroll
  for (int e = 0; e < NTRI; ++e) {
    float2 v = mc[((g*GROUP)*NTRI + e)*128 + tid];
    Ar[e] = v.x; Ai[e] = v.y;
  }
  for (int n = 1; n < GROUP; ++n) {
    const float2* Mn = mc + (size_t)((g*GROUP + n)*NTRI)*128;
    // Acc <- Mn * Acc, rows in descending order, per-row temp
    #pragma unroll
    for (int L = 8; L >= 0; --L) {
      float Br[9], Bi[9];
      #pragma unroll
      for (int r = 0; r <= L; ++r) {
        float2 v = Mn[TRI(L,r)*128 + tid];
        Br[r] = v.x; Bi[r] = v.y;
      }
      float tr[9], ti[9];
      #pragma unroll
      for (int q = 0; q <= L; ++q) {
        float sr = 0.f, si = 0.f;
        #pragma unroll
        for (int r = q; r <= L; ++r) {
          float xr = Ar[TRI(r,q)], xi = Ai[TRI(r,q)];
          sr += Br[r]*xr - Bi[r]*xi;
          si += Br[r]*xi + Bi[r]*xr;
        }
        tr[q] = sr; ti[q] = si;
      }
      #pragma unroll
      for (int q = 0; q <= L; ++q) { Ar[TRI(L,q)] = tr[q]; Ai[TRI(L,q)] = ti[q]; }
    }
  }
  #pragma unroll
  for (int e = 0; e < NTRI; ++e)
    mg[(g*NTRI + e)*128 + tid] = make_float2(Ar[e], Ai[e]);
}

// --------------------------------------- final scan + inverse DFT + write --
__global__ __launch_bounds__(128)
void sk_final(const float2* __restrict__ mg, float* __restrict__ out)
{
  __shared__ float Ur[128], Ui[128];
  __shared__ float ct[128], st[128];
  const int tid = threadIdx.x;   // = frequency k

  float vr[9], vi[9];
  #pragma unroll
  for (int L = 0; L <= 8; ++L) { vr[L] = 0.f; vi[L] = 0.f; }
  vr[0] = 1.0f;    // DFT of delta init, level 0 stays constant

  for (int g = 0; g < NGROUP; ++g) {
    float Gr[NTRI], Gi[NTRI];
    #pragma unroll
    for (int e = 0; e < NTRI; ++e) {
      float2 v = mg[(g*NTRI + e)*128 + tid];
      Gr[e] = v.x; Gi[e] = v.y;
    }
    // v <- G v, in-place descending L
    #pragma unroll
    for (int L = 8; L >= 0; --L) {
      float sr = 0.f, si = 0.f;
      #pragma unroll
      for (int q = 0; q <= L; ++q) {
        float xr = vr[q], xi = vi[q];
        sr += Gr[TRI(L,q)]*xr - Gi[TRI(L,q)]*xi;
        si += Gr[TRI(L,q)]*xi + Gi[TRI(L,q)]*xr;
      }
      vr[L] = sr; vi[L] = si;
    }
  }

  Ur[tid] = vr[8]; Ui[tid] = vi[8];
  float th = 6.28318530717958647692f * (float)tid / 128.0f;
  ct[tid] = cosf(th); st[tid] = sinf(th);
  __syncthreads();

  // out[j] = (1/128) sum_k Re(U_k e^{+2pi i jk/128})
  float acc = 0.f;
  for (int k = 0; k < 128; ++k) {
    int w = (tid * k) & 127;
    acc += Ur[k]*ct[w] - Ui[k]*st[w];
  }
  out[tid] = acc * (1.0f/128.0f);
}

// ---------------------------------------------------------------- launch ---
extern "C" void kernel_launch(void* const* d_in, const int* in_sizes, int n_in,
                              void* d_out, int out_size, void* d_ws, size_t ws_size,
                              hipStream_t stream)
{
  const int*   seq = (const int*)d_in[0];
  const float* hw  = (const float*)d_in[1];
  const float* sw  = (const float*)d_in[2];

  char* base = (char*)d_ws;
  float2* phat = (float2*)(base + OFF_PHAT);
  float2* ab   = (float2*)(base + OFF_AB);
  float2* mc   = (float2*)(base + OFF_MC);
  float2* mg   = (float2*)(base + OFF_MG);

  sk_setup<<<1, 1024, 0, stream>>>(seq, hw, sw, phat, ab);
  sk_chunk<<<NCHUNK, 128, 0, stream>>>(seq, phat, ab, mc);
  sk_group<<<NGROUP, 128, 0, stream>>>(mc, mg);
  sk_final<<<1, 128, 0, stream>>>(mg, (float*)d_out);
}

// Round 2
// 196.100 us; speedup vs baseline: 1.8009x; 1.8009x over previous
//
#include <hip/hip_runtime.h>
#include <math.h>

#define DDIM 128
#define NSEQ 8192
#define CHUNK 32
#define NCHUNK 256   // 8192/32
#define GROUP 8
#define NGROUP 32    // 256/8
#define NTRI 45      // lower-triangular entries (L,q), q<=L, L=0..8

#define TRI(L,q) ((L)*((L)+1)/2 + (q))

// ws layout (bytes)
#define OFF_PHAT 0                    // float2 [4][8][128]   = 32768 B
#define OFF_AB   32768                // float2 [8192][8]     = 524288 B
#define OFF_MC   557056               // float2 [256][45][128]= 11796480 B
#define OFF_MG   12353536             // float2 [32][45][128] = 1474560 B
// total ~13.2 MB

// ---------------------------------------------------------- reg helpers ----
__device__ __forceinline__ void loadG(const float2* __restrict__ p, int tid,
                                      float (&R)[NTRI], float (&I)[NTRI]) {
#pragma unroll
  for (int e = 0; e < NTRI; ++e) {
    float2 t = p[e*128 + tid];
    R[e] = t.x; I[e] = t.y;
  }
}

// v <- G v  (9x9 lower-triangular complex, in-place descending L)
__device__ __forceinline__ void matvec(const float (&GR)[NTRI], const float (&GI)[NTRI],
                                       float (&vr)[9], float (&vi)[9]) {
#pragma unroll
  for (int L = 8; L >= 0; --L) {
    float sr = 0.f, si = 0.f;
#pragma unroll
    for (int q = 0; q <= L; ++q) {
      float xr = vr[q], xi = vi[q];
      sr += GR[TRI(L,q)]*xr - GI[TRI(L,q)]*xi;
      si += GR[TRI(L,q)]*xi + GI[TRI(L,q)]*xr;
    }
    vr[L] = sr; vi[L] = si;
  }
}

// Acc <- B * Acc  (both lower-triangular, in-place descending L)
__device__ __forceinline__ void matmul(const float (&BR)[NTRI], const float (&BI)[NTRI],
                                       float (&Ar)[NTRI], float (&Ai)[NTRI]) {
#pragma unroll
  for (int L = 8; L >= 0; --L) {
    float tr[9], ti[9];
#pragma unroll
    for (int q = 0; q <= L; ++q) {
      float sr = 0.f, si = 0.f;
#pragma unroll
      for (int r = q; r <= L; ++r) {
        float br = BR[TRI(L,r)], bi = BI[TRI(L,r)];
        float ar = Ar[TRI(r,q)], ai = Ai[TRI(r,q)];
        sr += br*ar - bi*ai;
        si += br*ai + bi*ar;
      }
      tr[q] = sr; ti[q] = si;
    }
#pragma unroll
    for (int q = 0; q <= L; ++q) { Ar[TRI(L,q)] = tr[q]; Ai[TRI(L,q)] = ti[q]; }
  }
}

// ------------------------------------------------------------- phat ----
__global__ __launch_bounds__(1024)
void sk_phat(const float* __restrict__ hw,   // [8][128][4]
             float2* __restrict__ phat)      // out [4][8][128]
{
  __shared__ float probs[32*128];
  __shared__ float twc[128], tws[128];
  const int tid  = threadIdx.x;
  const int wave = tid >> 6, lane = tid & 63;

  // softmax over d for each (p,c) row; one wave per row-pair
  for (int r = wave; r < 32; r += 16) {
    const int p = r >> 2, c = r & 3;
    float h0 = hw[p*512 + lane*4 + c];
    float h1 = hw[p*512 + (lane+64)*4 + c];
    float mx = fmaxf(h0, h1);
    #pragma unroll
    for (int off = 1; off < 64; off <<= 1) mx = fmaxf(mx, __shfl_xor(mx, off));
    float e0 = expf(h0 - mx), e1 = expf(h1 - mx);
    float s = e0 + e1;
    #pragma unroll
    for (int off = 1; off < 64; off <<= 1) s += __shfl_xor(s, off);
    float inv = 1.0f / s;
    probs[r*128 + lane]      = e0 * inv;
    probs[r*128 + lane + 64] = e1 * inv;
  }
  if (tid < 128) {
    float th = 6.28318530717958647692f * (float)tid / 128.0f;
    twc[tid] = cosf(th);
    tws[tid] = sinf(th);
  }
  __syncthreads();

  // forward DFT: phat[c][p][k] = sum_j probs[r][j] e^{-2pi i jk/128}
  for (int o = tid; o < 4096; o += 1024) {
    const int r = o >> 7, k = o & 127;
    const int p = r >> 2, c = r & 3;
    float ar = 0.f, ai = 0.f;
    for (int j = 0; j < 128; ++j) {
      float pv = probs[r*128 + j];
      int w = (j * k) & 127;
      ar += pv * twc[w];
      ai -= pv * tws[w];
    }
    phat[(c*8 + p)*128 + k] = make_float2(ar, ai);
  }
}

// --------------------------------------------------------------- ab ----
__global__ __launch_bounds__(256)
void sk_ab(const int* __restrict__ seq,
           const float* __restrict__ sw,    // [8][4]
           float2* __restrict__ ab)         // out [8192][8]
{
  int n = blockIdx.x * 256 + threadIdx.x;
  const int total = NSEQ * 8;
  for (; n < total; n += gridDim.x * 256) {
    const int i = n >> 3, Lm1 = n & 7, L = Lm1 + 1;
    int c = seq[i];
    bool valid = (c >= 0) && (c < 4);
    int cc = min(max(c, 0), 3);
    bool gate = valid && (L <= i + 1);
    float z  = (float)L / (float)(i + 1);
    float sg = 1.0f / (1.0f + expf(-sw[Lm1*4 + cc]));
    float a = gate ? (1.0f - z) : 1.0f;
    float b = gate ? (z * sg) : 0.0f;
    ab[n] = make_float2(a, b);
  }
}

// ------------------------------------------------------- chunk matrices ----
__global__ __launch_bounds__(128, 1)
void sk_chunk(const int* __restrict__ seq,
              const float2* __restrict__ phat_g,
              const float2* __restrict__ ab_g,
              float2* __restrict__ mc)   // out [chunk][entry][k]
{
  __shared__ float2 phS[4096];      // [c][p][k]
  __shared__ float2 abS[CHUNK*8];
  __shared__ int    chS[CHUNK];
  const int tid = threadIdx.x;
  const int m   = blockIdx.x;

  for (int i2 = tid; i2 < 4096; i2 += 128)     phS[i2] = phat_g[i2];
  for (int i2 = tid; i2 < CHUNK*8; i2 += 128)  abS[i2] = ab_g[m*CHUNK*8 + i2];
  if (tid < CHUNK) chS[tid] = seq[m*CHUNK + tid];
  __syncthreads();

  float Mr[NTRI], Mi[NTRI];
  #pragma unroll
  for (int e = 0; e < NTRI; ++e) { Mr[e] = 0.f; Mi[e] = 0.f; }
  #pragma unroll
  for (int L = 0; L <= 8; ++L) Mr[TRI(L,L)] = 1.0f;

  for (int t = 0; t < CHUNK; ++t) {
    const int c = chS[t];
    // row_L <- a*row_L + b*Phat[L-1]*row_{L-1}, in-place descending L
    #pragma unroll
    for (int L = 8; L >= 1; --L) {
      float2 abv = abS[t*8 + (L-1)];
      float2 Pv  = phS[(c*8 + (L-1))*128 + tid];
      const float a = abv.x, b = abv.y;
      #pragma unroll
      for (int q = 0; q < L; ++q) {
        float xr = Mr[TRI(L-1,q)], xi = Mi[TRI(L-1,q)];
        float tr = Pv.x*xr - Pv.y*xi;
        float ti = Pv.x*xi + Pv.y*xr;
        Mr[TRI(L,q)] = a*Mr[TRI(L,q)] + b*tr;
        Mi[TRI(L,q)] = a*Mi[TRI(L,q)] + b*ti;
      }
      Mr[TRI(L,L)] *= a;
      Mi[TRI(L,L)] *= a;
    }
  }
  #pragma unroll
  for (int e = 0; e < NTRI; ++e)
    mc[(m*NTRI + e)*128 + tid] = make_float2(Mr[e], Mi[e]);
}

// -------------------------------------------------- combine 8 chunks -> 1 --
// Register double-buffered: prefetch M_{n+1} while multiplying M_n.
__global__ __launch_bounds__(128, 1)
void sk_group(const float2* __restrict__ mc, float2* __restrict__ mg)
{
  const int tid = threadIdx.x;
  const int g   = blockIdx.x;
  const float2* basep = mc + (size_t)g * GROUP * NTRI * 128;

  float Ar[NTRI], Ai[NTRI];   // accumulator = product so far
  float Xr[NTRI], Xi[NTRI];   // prefetch buffer A
  float Yr[NTRI], Yi[NTRI];   // prefetch buffer B

  loadG(basep, tid, Ar, Ai);                         // n=0 -> Acc
  loadG(basep + (size_t)1*NTRI*128, tid, Xr, Xi);    // n=1 -> X

  // n=1..7, alternating buffers, all compile-time
  loadG(basep + (size_t)2*NTRI*128, tid, Yr, Yi);  matmul(Xr, Xi, Ar, Ai);  // use n=1, fetch n=2
  loadG(basep + (size_t)3*NTRI*128, tid, Xr, Xi);  matmul(Yr, Yi, Ar, Ai);  // use n=2, fetch n=3
  loadG(basep + (size_t)4*NTRI*128, tid, Yr, Yi);  matmul(Xr, Xi, Ar, Ai);  // use n=3, fetch n=4
  loadG(basep + (size_t)5*NTRI*128, tid, Xr, Xi);  matmul(Yr, Yi, Ar, Ai);  // use n=4, fetch n=5
  loadG(basep + (size_t)6*NTRI*128, tid, Yr, Yi);  matmul(Xr, Xi, Ar, Ai);  // use n=5, fetch n=6
  loadG(basep + (size_t)7*NTRI*128, tid, Xr, Xi);  matmul(Yr, Yi, Ar, Ai);  // use n=6, fetch n=7
  matmul(Xr, Xi, Ar, Ai);                                                   // use n=7

  #pragma unroll
  for (int e = 0; e < NTRI; ++e)
    mg[(g*NTRI + e)*128 + tid] = make_float2(Ar[e], Ai[e]);
}

// --------------------------------------- final scan + inverse DFT + write --
// Register double-buffered scan over the 32 group matrices.
__global__ __launch_bounds__(128, 1)
void sk_final(const float2* __restrict__ mg, float* __restrict__ out)
{
  __shared__ float Ur[128], Ui[128];
  __shared__ float ct[128], st[128];
  const int tid = threadIdx.x;   // = frequency k

  float vr[9], vi[9];
  #pragma unroll
  for (int L = 0; L <= 8; ++L) { vr[L] = 0.f; vi[L] = 0.f; }
  vr[0] = 1.0f;    // DFT of delta init

  float Ar[NTRI], Ai[NTRI], Br[NTRI], Bi[NTRI];

  loadG(mg, tid, Ar, Ai);                              // g=0
  for (int g = 0; g < NGROUP; g += 2) {
    loadG(mg + (size_t)(g+1)*NTRI*128, tid, Br, Bi);   // prefetch g+1
    matvec(Ar, Ai, vr, vi);                            // consume g
    if (g + 2 < NGROUP)
      loadG(mg + (size_t)(g+2)*NTRI*128, tid, Ar, Ai); // prefetch g+2
    matvec(Br, Bi, vr, vi);                            // consume g+1
  }

  Ur[tid] = vr[8]; Ui[tid] = vi[8];
  float th = 6.28318530717958647692f * (float)tid / 128.0f;
  ct[tid] = cosf(th); st[tid] = sinf(th);
  __syncthreads();

  // out[j] = (1/128) sum_k Re(U_k e^{+2pi i jk/128})
  float acc = 0.f;
  for (int k = 0; k < 128; ++k) {
    int w = (tid * k) & 127;
    acc += Ur[k]*ct[w] - Ui[k]*st[w];
  }
  out[tid] = acc * (1.0f/128.0f);
}

// ---------------------------------------------------------------- launch ---
extern "C" void kernel_launch(void* const* d_in, const int* in_sizes, int n_in,
                              void* d_out, int out_size, void* d_ws, size_t ws_size,
                              hipStream_t stream)
{
  const int*   seq = (const int*)d_in[0];
  const float* hw  = (const float*)d_in[1];
  const float* sw  = (const float*)d_in[2];

  char* base = (char*)d_ws;
  float2* phat = (float2*)(base + OFF_PHAT);
  float2* ab   = (float2*)(base + OFF_AB);
  float2* mc   = (float2*)(base + OFF_MC);
  float2* mg   = (float2*)(base + OFF_MG);

  sk_ab<<<64, 256, 0, stream>>>(seq, sw, ab);
  sk_phat<<<1, 1024, 0, stream>>>(hw, phat);
  sk_chunk<<<NCHUNK, 128, 0, stream>>>(seq, phat, ab, mc);
  sk_group<<<NGROUP, 128, 0, stream>>>(mc, mg);
  sk_final<<<1, 128, 0, stream>>>(mg, (float*)d_out);
}

// Round 3
// 173.805 us; speedup vs baseline: 2.0319x; 1.1283x over previous
//
#include <hip/hip_runtime.h>
#include <math.h>

#define DDIM 128
#define NSEQ 8192
#define CHUNK 16
#define NCHUNK 512   // 8192/16
#define GROUP 16
#define NGROUP 32    // 512/16
#define NTRI 45      // lower-triangular entries (L,q), q<=L, L=0..8

#define TRI(L,q) ((L)*((L)+1)/2 + (q))

// ws layout (bytes)
#define OFF_PHAT 0                      // float2 [4][8][128]    = 32768 B
#define OFF_AB   32768                  // float2 [8192][8]      = 524288 B
#define OFF_MC   557056                 // float2 [512][45][128] = 23592960 B
#define OFF_MG   24150016               // float2 [32][45][128]  = 1474560 B
// total ~25.6 MB

// ---------------------------------------------------------- reg helpers ----
__device__ __forceinline__ void loadG(const float2* __restrict__ p, int tid,
                                      float (&R)[NTRI], float (&I)[NTRI]) {
#pragma unroll
  for (int e = 0; e < NTRI; ++e) {
    float2 t = p[e*128 + tid];
    R[e] = t.x; I[e] = t.y;
  }
}

// v <- G v  (9x9 lower-triangular complex, in-place descending L)
__device__ __forceinline__ void matvec(const float (&GR)[NTRI], const float (&GI)[NTRI],
                                       float (&vr)[9], float (&vi)[9]) {
#pragma unroll
  for (int L = 8; L >= 0; --L) {
    float sr = 0.f, si = 0.f;
#pragma unroll
    for (int q = 0; q <= L; ++q) {
      float xr = vr[q], xi = vi[q];
      sr += GR[TRI(L,q)]*xr - GI[TRI(L,q)]*xi;
      si += GR[TRI(L,q)]*xi + GI[TRI(L,q)]*xr;
    }
    vr[L] = sr; vi[L] = si;
  }
}

// Acc <- B * Acc  (both lower-triangular, in-place descending L)
__device__ __forceinline__ void matmul(const float (&BR)[NTRI], const float (&BI)[NTRI],
                                       float (&Ar)[NTRI], float (&Ai)[NTRI]) {
#pragma unroll
  for (int L = 8; L >= 0; --L) {
    float tr[9], ti[9];
#pragma unroll
    for (int q = 0; q <= L; ++q) {
      float sr = 0.f, si = 0.f;
#pragma unroll
      for (int r = q; r <= L; ++r) {
        float br = BR[TRI(L,r)], bi = BI[TRI(L,r)];
        float ar = Ar[TRI(r,q)], ai = Ai[TRI(r,q)];
        sr += br*ar - bi*ai;
        si += br*ai + bi*ar;
      }
      tr[q] = sr; ti[q] = si;
    }
#pragma unroll
    for (int q = 0; q <= L; ++q) { Ar[TRI(L,q)] = tr[q]; Ai[TRI(L,q)] = ti[q]; }
  }
}

// ----------------------------------------------------- setup (phat + ab) ---
// blocks 0..31  : one (p,c) row each -> softmax over d, forward DFT -> phat
// blocks 32..95 : ab coefficient table
__global__ __launch_bounds__(128)
void sk_setup(const int* __restrict__ seq,
              const float* __restrict__ hw,    // [8][128][4]
              const float* __restrict__ sw,    // [8][4]
              float2* __restrict__ phat,       // out [4][8][128]
              float2* __restrict__ ab)         // out [8192][8]
{
  const int tid = threadIdx.x;
  const int bid = blockIdx.x;

  if (bid < 32) {
    __shared__ float probs[128];
    __shared__ float ct[128], st[128];
    __shared__ float red[4];
    const int r = bid, p = r >> 2, c = r & 3;
    const int wave = tid >> 6, lane = tid & 63;

    float h = hw[p*512 + tid*4 + c];
    // max over 128 threads (2 waves)
    float mx = h;
    #pragma unroll
    for (int off = 1; off < 64; off <<= 1) mx = fmaxf(mx, __shfl_xor(mx, off));
    if (lane == 0) red[wave] = mx;
    __syncthreads();
    mx = fmaxf(red[0], red[1]);
    float e = expf(h - mx);
    float s = e;
    #pragma unroll
    for (int off = 1; off < 64; off <<= 1) s += __shfl_xor(s, off);
    if (lane == 0) red[2 + wave] = s;
    // twiddles
    float th = 6.28318530717958647692f * (float)tid / 128.0f;
    ct[tid] = cosf(th); st[tid] = sinf(th);
    __syncthreads();
    s = red[2] + red[3];
    probs[tid] = e / s;
    __syncthreads();

    // DFT: thread k computes phat[c][p][k]
    float ar = 0.f, ai = 0.f;
    for (int j = 0; j < 128; ++j) {
      float pv = probs[j];
      int w = (j * tid) & 127;
      ar += pv * ct[w];
      ai -= pv * st[w];
    }
    phat[(c*8 + p)*128 + tid] = make_float2(ar, ai);
  } else {
    // ab table: a = gate ? 1-z : 1 ; b = gate ? z*sigmoid(sw[L-1][c]) : 0
    const int total = NSEQ * 8;
    for (int n = (bid - 32)*128 + tid; n < total; n += 64*128) {
      const int i = n >> 3, Lm1 = n & 7, L = Lm1 + 1;
      int cc0 = seq[i];
      bool valid = (cc0 >= 0) && (cc0 < 4);
      int cc = min(max(cc0, 0), 3);
      bool gate = valid && (L <= i + 1);
      float z  = (float)L / (float)(i + 1);
      float sg = 1.0f / (1.0f + expf(-sw[Lm1*4 + cc]));
      float a = gate ? (1.0f - z) : 1.0f;
      float b = gate ? (z * sg) : 0.0f;
      ab[n] = make_float2(a, b);
    }
  }
}

// ------------------------------------------------------- chunk matrices ----
// Each block builds the 9x9 lower-triangular complex transfer matrix of its
// 16-step chunk, per frequency (lane = k). All M indices compile-time.
__global__ __launch_bounds__(128)
void sk_chunk(const int* __restrict__ seq,
              const float2* __restrict__ phat_g,
              const float2* __restrict__ ab_g,
              float2* __restrict__ mc)   // out [chunk][entry][k]
{
  __shared__ float2 phS[4096];      // [c][p][k]  (32 KB)
  __shared__ float2 abS[CHUNK*8];
  __shared__ int    chS[CHUNK];
  const int tid = threadIdx.x;
  const int m   = blockIdx.x;

  // stage phat as float4 (2 float2 per load)
  {
    const float4* src = (const float4*)phat_g;
    float4* dst = (float4*)phS;
    for (int i2 = tid; i2 < 2048; i2 += 128) dst[i2] = src[i2];
  }
  for (int i2 = tid; i2 < CHUNK*8; i2 += 128) abS[i2] = ab_g[m*CHUNK*8 + i2];
  if (tid < CHUNK) chS[tid] = seq[m*CHUNK + tid];
  __syncthreads();

  float Mr[NTRI], Mi[NTRI];
  #pragma unroll
  for (int e = 0; e < NTRI; ++e) { Mr[e] = 0.f; Mi[e] = 0.f; }
  #pragma unroll
  for (int L = 0; L <= 8; ++L) Mr[TRI(L,L)] = 1.0f;

  for (int t = 0; t < CHUNK; ++t) {
    const int c = chS[t];
    // row_L <- a*row_L + b*Phat[L-1]*row_{L-1}, in-place descending L
    #pragma unroll
    for (int L = 8; L >= 1; --L) {
      float2 abv = abS[t*8 + (L-1)];
      float2 Pv  = phS[(c*8 + (L-1))*128 + tid];
      const float a = abv.x, b = abv.y;
      const float bPr = b * Pv.x, bPi = b * Pv.y;
      #pragma unroll
      for (int q = 0; q < L; ++q) {
        float xr = Mr[TRI(L-1,q)], xi = Mi[TRI(L-1,q)];
        Mr[TRI(L,q)] = a*Mr[TRI(L,q)] + (bPr*xr - bPi*xi);
        Mi[TRI(L,q)] = a*Mi[TRI(L,q)] + (bPr*xi + bPi*xr);
      }
      Mr[TRI(L,L)] *= a;
      Mi[TRI(L,L)] *= a;
    }
  }
  #pragma unroll
  for (int e = 0; e < NTRI; ++e)
    mc[(m*NTRI + e)*128 + tid] = make_float2(Mr[e], Mi[e]);
}

// ------------------------------------------------- combine 16 chunks -> 1 --
// Register double-buffered: prefetch M_{n+1} while multiplying M_n.
__global__ __launch_bounds__(128, 1)
void sk_group(const float2* __restrict__ mc, float2* __restrict__ mg)
{
  const int tid = threadIdx.x;
  const int g   = blockIdx.x;
  const float2* b = mc + (size_t)g * GROUP * NTRI * 128;
  #define MAT(n) (b + (size_t)(n)*NTRI*128)

  float Ar[NTRI], Ai[NTRI];   // accumulator = product so far
  float Xr[NTRI], Xi[NTRI];   // prefetch buffer A
  float Yr[NTRI], Yi[NTRI];   // prefetch buffer B

  loadG(MAT(0), tid, Ar, Ai);
  loadG(MAT(1), tid, Xr, Xi);

  loadG(MAT(2),  tid, Yr, Yi);  matmul(Xr, Xi, Ar, Ai);   // M1
  loadG(MAT(3),  tid, Xr, Xi);  matmul(Yr, Yi, Ar, Ai);   // M2
  loadG(MAT(4),  tid, Yr, Yi);  matmul(Xr, Xi, Ar, Ai);   // M3
  loadG(MAT(5),  tid, Xr, Xi);  matmul(Yr, Yi, Ar, Ai);   // M4
  loadG(MAT(6),  tid, Yr, Yi);  matmul(Xr, Xi, Ar, Ai);   // M5
  loadG(MAT(7),  tid, Xr, Xi);  matmul(Yr, Yi, Ar, Ai);   // M6
  loadG(MAT(8),  tid, Yr, Yi);  matmul(Xr, Xi, Ar, Ai);   // M7
  loadG(MAT(9),  tid, Xr, Xi);  matmul(Yr, Yi, Ar, Ai);   // M8
  loadG(MAT(10), tid, Yr, Yi);  matmul(Xr, Xi, Ar, Ai);   // M9
  loadG(MAT(11), tid, Xr, Xi);  matmul(Yr, Yi, Ar, Ai);   // M10
  loadG(MAT(12), tid, Yr, Yi);  matmul(Xr, Xi, Ar, Ai);   // M11
  loadG(MAT(13), tid, Xr, Xi);  matmul(Yr, Yi, Ar, Ai);   // M12
  loadG(MAT(14), tid, Yr, Yi);  matmul(Xr, Xi, Ar, Ai);   // M13
  loadG(MAT(15), tid, Xr, Xi);  matmul(Yr, Yi, Ar, Ai);   // M14
  matmul(Xr, Xi, Ar, Ai);                                 // M15
  #undef MAT

  #pragma unroll
  for (int e = 0; e < NTRI; ++e)
    mg[(g*NTRI + e)*128 + tid] = make_float2(Ar[e], Ai[e]);
}

// --------------------------------------- final scan + inverse DFT + write --
// Register double-buffered scan over the 32 group matrices.
__global__ __launch_bounds__(128, 1)
void sk_final(const float2* __restrict__ mg, float* __restrict__ out)
{
  __shared__ float Ur[128], Ui[128];
  __shared__ float ct[128], st[128];
  const int tid = threadIdx.x;   // = frequency k

  float vr[9], vi[9];
  #pragma unroll
  for (int L = 0; L <= 8; ++L) { vr[L] = 0.f; vi[L] = 0.f; }
  vr[0] = 1.0f;    // DFT of delta init

  float Ar[NTRI], Ai[NTRI], Br[NTRI], Bi[NTRI];

  loadG(mg, tid, Ar, Ai);                              // g=0
  for (int g = 0; g < NGROUP; g += 2) {
    loadG(mg + (size_t)(g+1)*NTRI*128, tid, Br, Bi);   // prefetch g+1
    matvec(Ar, Ai, vr, vi);                            // consume g
    if (g + 2 < NGROUP)
      loadG(mg + (size_t)(g+2)*NTRI*128, tid, Ar, Ai); // prefetch g+2
    matvec(Br, Bi, vr, vi);                            // consume g+1
  }

  Ur[tid] = vr[8]; Ui[tid] = vi[8];
  float th = 6.28318530717958647692f * (float)tid / 128.0f;
  ct[tid] = cosf(th); st[tid] = sinf(th);
  __syncthreads();

  // out[j] = (1/128) sum_k Re(U_k e^{+2pi i jk/128})
  float acc = 0.f;
  for (int k = 0; k < 128; ++k) {
    int w = (tid * k) & 127;
    acc += Ur[k]*ct[w] - Ui[k]*st[w];
  }
  out[tid] = acc * (1.0f/128.0f);
}

// ---------------------------------------------------------------- launch ---
extern "C" void kernel_launch(void* const* d_in, const int* in_sizes, int n_in,
                              void* d_out, int out_size, void* d_ws, size_t ws_size,
                              hipStream_t stream)
{
  const int*   seq = (const int*)d_in[0];
  const float* hw  = (const float*)d_in[1];
  const float* sw  = (const float*)d_in[2];

  char* base = (char*)d_ws;
  float2* phat = (float2*)(base + OFF_PHAT);
  float2* ab   = (float2*)(base + OFF_AB);
  float2* mc   = (float2*)(base + OFF_MC);
  float2* mg   = (float2*)(base + OFF_MG);

  sk_setup<<<96, 128, 0, stream>>>(seq, hw, sw, phat, ab);
  sk_chunk<<<NCHUNK, 128, 0, stream>>>(seq, phat, ab, mc);
  sk_group<<<NGROUP, 128, 0, stream>>>(mc, mg);
  sk_final<<<1, 128, 0, stream>>>(mg, (float*)d_out);
}

// Round 4
// 139.966 us; speedup vs baseline: 2.5231x; 1.2418x over previous
//
#include <hip/hip_runtime.h>
#include <math.h>

#define DDIM 128
#define NSEQ 8192
#define SUB 16        // steps per unit
#define SEG 64        // steps per seg block (4 units)
#define NSEGB 128     // 8192/64 seg blocks -> 128 matrices
#define COMB 16       // matrices folded per comb1 block
#define NCOMB 8       // comb1 blocks -> 8 matrices
#define NTRI 45       // lower-triangular entries (L,q), q<=L, L=0..8

#define TRI(L,q) ((L)*((L)+1)/2 + (q))

// ws layout (bytes)
#define OFF_PHAT 0                      // float2 [4][8][128]    = 32768
#define OFF_AB   32768                  // float2 [8192][8]      = 524288
#define OFF_MSEG 557056                 // float2 [128][45][128] = 5898240
#define OFF_MG2  6455296                // float2 [8][45][128]   = 368640
// total ~6.8 MB

// ---------------------------------------------------------- reg helpers ----
__device__ __forceinline__ void loadG(const float2* __restrict__ p, int fq,
                                      float (&R)[NTRI], float (&I)[NTRI]) {
#pragma unroll
  for (int e = 0; e < NTRI; ++e) {
    float2 t = p[e*128 + fq];
    R[e] = t.x; I[e] = t.y;
  }
}

// v <- G v  (9x9 lower-triangular complex, in-place descending L)
__device__ __forceinline__ void matvec(const float (&GR)[NTRI], const float (&GI)[NTRI],
                                       float (&vr)[9], float (&vi)[9]) {
#pragma unroll
  for (int L = 8; L >= 0; --L) {
    float sr = 0.f, si = 0.f;
#pragma unroll
    for (int q = 0; q <= L; ++q) {
      float xr = vr[q], xi = vi[q];
      sr += GR[TRI(L,q)]*xr - GI[TRI(L,q)]*xi;
      si += GR[TRI(L,q)]*xi + GI[TRI(L,q)]*xr;
    }
    vr[L] = sr; vi[L] = si;
  }
}

// Acc <- B * Acc  (both lower-triangular, in-place descending L)
__device__ __forceinline__ void matmul(const float (&BR)[NTRI], const float (&BI)[NTRI],
                                       float (&Ar)[NTRI], float (&Ai)[NTRI]) {
#pragma unroll
  for (int L = 8; L >= 0; --L) {
    float tr[9], ti[9];
#pragma unroll
    for (int q = 0; q <= L; ++q) {
      float sr = 0.f, si = 0.f;
#pragma unroll
      for (int r = q; r <= L; ++r) {
        float br = BR[TRI(L,r)], bi = BI[TRI(L,r)];
        float ar = Ar[TRI(r,q)], ai = Ai[TRI(r,q)];
        sr += br*ar - bi*ai;
        si += br*ai + bi*ar;
      }
      tr[q] = sr; ti[q] = si;
    }
#pragma unroll
    for (int q = 0; q <= L; ++q) { Ar[TRI(L,q)] = tr[q]; Ai[TRI(L,q)] = ti[q]; }
  }
}

// ----------------------------------------------------- setup (phat + ab) ---
// blocks 0..31  : one (p,c) row each -> softmax over d, forward DFT -> phat
// blocks 32..95 : ab coefficient table
__global__ __launch_bounds__(128)
void sk_setup(const int* __restrict__ seq,
              const float* __restrict__ hw,    // [8][128][4]
              const float* __restrict__ sw,    // [8][4]
              float2* __restrict__ phat,       // out [4][8][128]
              float2* __restrict__ ab)         // out [8192][8]
{
  const int tid = threadIdx.x;
  const int bid = blockIdx.x;

  if (bid < 32) {
    __shared__ float probs[128];
    __shared__ float ct[128], st[128];
    __shared__ float red[4];
    const int r = bid, p = r >> 2, c = r & 3;
    const int wave = tid >> 6, lane = tid & 63;

    float h = hw[p*512 + tid*4 + c];
    float mx = h;
    #pragma unroll
    for (int off = 1; off < 64; off <<= 1) mx = fmaxf(mx, __shfl_xor(mx, off));
    if (lane == 0) red[wave] = mx;
    __syncthreads();
    mx = fmaxf(red[0], red[1]);
    float e = expf(h - mx);
    float s = e;
    #pragma unroll
    for (int off = 1; off < 64; off <<= 1) s += __shfl_xor(s, off);
    if (lane == 0) red[2 + wave] = s;
    float th = 6.28318530717958647692f * (float)tid / 128.0f;
    ct[tid] = cosf(th); st[tid] = sinf(th);
    __syncthreads();
    s = red[2] + red[3];
    probs[tid] = e / s;
    __syncthreads();

    float ar = 0.f, ai = 0.f;
    for (int j = 0; j < 128; ++j) {
      float pv = probs[j];
      int w = (j * tid) & 127;
      ar += pv * ct[w];
      ai -= pv * st[w];
    }
    phat[(c*8 + p)*128 + tid] = make_float2(ar, ai);
  } else {
    const int total = NSEQ * 8;
    for (int n = (bid - 32)*128 + tid; n < total; n += 64*128) {
      const int i = n >> 3, Lm1 = n & 7, L = Lm1 + 1;
      int cc0 = seq[i];
      bool valid = (cc0 >= 0) && (cc0 < 4);
      int cc = min(max(cc0, 0), 3);
      bool gate = valid && (L <= i + 1);
      float z  = (float)L / (float)(i + 1);
      float sg = 1.0f / (1.0f + expf(-sw[Lm1*4 + cc]));
      float a = gate ? (1.0f - z) : 1.0f;
      float b = gate ? (z * sg) : 0.0f;
      ab[n] = make_float2(a, b);
    }
  }
}

// ------------------------------------------- 64-step segment matrices -----
// 128 blocks x 512 threads: unit u = tid>>7 builds a 16-step matrix in regs,
// then 2-level in-block tree (via LDS) -> one 64-step matrix per block.
__global__ __launch_bounds__(512, 1)
void sk_seg(const int* __restrict__ seq,
            const float2* __restrict__ phat_g,
            const float2* __restrict__ ab_g,
            float2* __restrict__ mseg)
{
  __shared__ float2 phS[4096];          // 32 KB  [c][p][k]
  __shared__ float2 abS[SEG*8];         // 4 KB
  __shared__ int    chS[SEG];
  __shared__ float2 tb[2][NTRI*128];    // 92 KB ping-pong tree buffers
  const int tid = threadIdx.x;
  const int u   = tid >> 7, fq = tid & 127;
  const int m   = blockIdx.x;

  {
    const float4* src = (const float4*)phat_g;
    float4* dst = (float4*)phS;
    for (int i = tid; i < 2048; i += 512) dst[i] = src[i];
  }
  for (int i = tid; i < SEG*8; i += 512) abS[i] = ab_g[m*SEG*8 + i];
  if (tid < SEG) chS[tid] = seq[m*SEG + tid];
  __syncthreads();

  float Mr[NTRI], Mi[NTRI];
  #pragma unroll
  for (int e = 0; e < NTRI; ++e) { Mr[e] = 0.f; Mi[e] = 0.f; }
  #pragma unroll
  for (int L = 0; L <= 8; ++L) Mr[TRI(L,L)] = 1.0f;

  const int t0 = u * SUB;
  for (int t = 0; t < SUB; ++t) {
    const int ts = t0 + t;
    const int c  = chS[ts];
    // row_L <- a*row_L + b*Phat[L-1]*row_{L-1}, in-place descending L
    #pragma unroll
    for (int L = 8; L >= 1; --L) {
      float2 abv = abS[ts*8 + (L-1)];
      float2 Pv  = phS[(c*8 + (L-1))*128 + fq];
      const float a = abv.x;
      const float bPr = abv.y * Pv.x, bPi = abv.y * Pv.y;
      #pragma unroll
      for (int q = 0; q < L; ++q) {
        float xr = Mr[TRI(L-1,q)], xi = Mi[TRI(L-1,q)];
        Mr[TRI(L,q)] = a*Mr[TRI(L,q)] + (bPr*xr - bPi*xi);
        Mi[TRI(L,q)] = a*Mi[TRI(L,q)] + (bPr*xi + bPi*xr);
      }
      Mr[TRI(L,L)] *= a;
      Mi[TRI(L,L)] *= a;
    }
  }

  // tree stage 1: units 1,3 publish; units 0,2 left-multiply
  if (u == 1 || u == 3) {
    float2* b = tb[u >> 1];
    #pragma unroll
    for (int e = 0; e < NTRI; ++e) b[e*128 + fq] = make_float2(Mr[e], Mi[e]);
  }
  __syncthreads();
  if (u == 0 || u == 2) {
    const float2* b = tb[u >> 1];
    float Br[NTRI], Bi[NTRI];
    #pragma unroll
    for (int e = 0; e < NTRI; ++e) { float2 t = b[e*128 + fq]; Br[e] = t.x; Bi[e] = t.y; }
    matmul(Br, Bi, Mr, Mi);
  }
  __syncthreads();
  // tree stage 2: unit 2 publishes P23; unit 0 forms P23*P01 and stores
  if (u == 2) {
    #pragma unroll
    for (int e = 0; e < NTRI; ++e) tb[1][e*128 + fq] = make_float2(Mr[e], Mi[e]);
  }
  __syncthreads();
  if (u == 0) {
    float Br[NTRI], Bi[NTRI];
    #pragma unroll
    for (int e = 0; e < NTRI; ++e) { float2 t = tb[1][e*128 + fq]; Br[e] = t.x; Bi[e] = t.y; }
    matmul(Br, Bi, Mr, Mi);
    #pragma unroll
    for (int e = 0; e < NTRI; ++e)
      mseg[((size_t)m*NTRI + e)*128 + fq] = make_float2(Mr[e], Mi[e]);
  }
}

// ------------------------------------------- fold 16 seg matrices -> 1 ----
// 8 blocks x 512 threads: unit u serially folds mats [16g+4u, +4), then the
// same 2-level in-block tree -> mg2[g].
__global__ __launch_bounds__(512, 1)
void sk_comb1(const float2* __restrict__ mseg, float2* __restrict__ mg2)
{
  __shared__ float2 tb[2][NTRI*128];    // 92 KB
  const int tid = threadIdx.x;
  const int u   = tid >> 7, fq = tid & 127;
  const int g   = blockIdx.x;
  const float2* bp = mseg + (size_t)(g*COMB + u*4) * NTRI * 128;

  float Ar[NTRI], Ai[NTRI], Br[NTRI], Bi[NTRI];
  loadG(bp, fq, Ar, Ai);
  loadG(bp + (size_t)1*NTRI*128, fq, Br, Bi);  matmul(Br, Bi, Ar, Ai);
  loadG(bp + (size_t)2*NTRI*128, fq, Br, Bi);  matmul(Br, Bi, Ar, Ai);
  loadG(bp + (size_t)3*NTRI*128, fq, Br, Bi);  matmul(Br, Bi, Ar, Ai);

  if (u == 1 || u == 3) {
    float2* b = tb[u >> 1];
    #pragma unroll
    for (int e = 0; e < NTRI; ++e) b[e*128 + fq] = make_float2(Ar[e], Ai[e]);
  }
  __syncthreads();
  if (u == 0 || u == 2) {
    const float2* b = tb[u >> 1];
    #pragma unroll
    for (int e = 0; e < NTRI; ++e) { float2 t = b[e*128 + fq]; Br[e] = t.x; Bi[e] = t.y; }
    matmul(Br, Bi, Ar, Ai);
  }
  __syncthreads();
  if (u == 2) {
    #pragma unroll
    for (int e = 0; e < NTRI; ++e) tb[1][e*128 + fq] = make_float2(Ar[e], Ai[e]);
  }
  __syncthreads();
  if (u == 0) {
    #pragma unroll
    for (int e = 0; e < NTRI; ++e) { float2 t = tb[1][e*128 + fq]; Br[e] = t.x; Bi[e] = t.y; }
    matmul(Br, Bi, Ar, Ai);
    #pragma unroll
    for (int e = 0; e < NTRI; ++e)
      mg2[((size_t)g*NTRI + e)*128 + fq] = make_float2(Ar[e], Ai[e]);
  }
}

// --------------------- final: 8-matrix mat-vec relay + inverse DFT --------
// 1 block x 512 threads. Unit u pre-loads mats 2u,2u+1 (loads issued at
// kernel start, hidden behind earlier units' matvecs). v = (Pi M) e0 is
// relayed through LDS; U_k = v[8]; then iDFT and write.
__global__ __launch_bounds__(512, 1)
void sk_fin(const float2* __restrict__ mg2, float* __restrict__ out)
{
  __shared__ float2 vS[9*128];
  __shared__ float Ur[128], Ui[128];
  __shared__ float ct[128], st[128];
  const int tid = threadIdx.x;
  const int u   = tid >> 7, fq = tid & 127;

  float Ar[NTRI], Ai[NTRI], Br[NTRI], Bi[NTRI];
  loadG(mg2 + (size_t)(2*u)  *NTRI*128, fq, Ar, Ai);
  loadG(mg2 + (size_t)(2*u+1)*NTRI*128, fq, Br, Bi);

  if (tid < 128) {
    float th = 6.28318530717958647692f * (float)tid / 128.0f;
    ct[tid] = cosf(th); st[tid] = sinf(th);
  }

  float vr[9], vi[9];
  if (u == 0) {
    // v = M0 * e0 = column 0 of M0
    #pragma unroll
    for (int L = 0; L <= 8; ++L) { vr[L] = Ar[TRI(L,0)]; vi[L] = Ai[TRI(L,0)]; }
    matvec(Br, Bi, vr, vi);
    #pragma unroll
    for (int L = 0; L <= 8; ++L) vS[L*128 + fq] = make_float2(vr[L], vi[L]);
  }
  __syncthreads();
  for (int uu = 1; uu < 4; ++uu) {
    if (u == uu) {
      #pragma unroll
      for (int L = 0; L <= 8; ++L) { float2 t = vS[L*128 + fq]; vr[L] = t.x; vi[L] = t.y; }
      matvec(Ar, Ai, vr, vi);
      matvec(Br, Bi, vr, vi);
      #pragma unroll
      for (int L = 0; L <= 8; ++L) vS[L*128 + fq] = make_float2(vr[L], vi[L]);
    }
    __syncthreads();
  }

  if (tid < 128) {
    float2 uv = vS[8*128 + tid];
    Ur[tid] = uv.x; Ui[tid] = uv.y;
  }
  __syncthreads();

  if (tid < 128) {
    // out[j] = (1/128) sum_k Re(U_k e^{+2pi i jk/128})
    float acc = 0.f;
    for (int k = 0; k < 128; ++k) {
      int w = (tid * k) & 127;
      acc += Ur[k]*ct[w] - Ui[k]*st[w];
    }
    out[tid] = acc * (1.0f/128.0f);
  }
}

// ---------------------------------------------------------------- launch ---
extern "C" void kernel_launch(void* const* d_in, const int* in_sizes, int n_in,
                              void* d_out, int out_size, void* d_ws, size_t ws_size,
                              hipStream_t stream)
{
  const int*   seq = (const int*)d_in[0];
  const float* hw  = (const float*)d_in[1];
  const float* sw  = (const float*)d_in[2];

  char* base = (char*)d_ws;
  float2* phat = (float2*)(base + OFF_PHAT);
  float2* ab   = (float2*)(base + OFF_AB);
  float2* mseg = (float2*)(base + OFF_MSEG);
  float2* mg2  = (float2*)(base + OFF_MG2);

  sk_setup<<<96, 128, 0, stream>>>(seq, hw, sw, phat, ab);
  sk_seg<<<NSEGB, 512, 0, stream>>>(seq, phat, ab, mseg);
  sk_comb1<<<NCOMB, 512, 0, stream>>>(mseg, mg2);
  sk_fin<<<1, 512, 0, stream>>>(mg2, (float*)d_out);
}